// Round 4
// baseline (3210.714 us; speedup 1.0000x reference)
//
#include <hip/hip_runtime.h>

#define BLK   256
#define Wd    128
#define NSAMP 8
#define NPS   (1 << 21)           // voxels per sample (128^3)
#define BN    (1 << 24)           // total voxels
#define NBLK  (BN / BLK)

// Tile: full-x rows, 8x8 in y/z -> 8192 voxels, 32 KiB LDS parents
#define TY 8
#define TZ 8
#define TVOX (128 * TY * TZ)                  // 8192
#define NTILES (NSAMP * (128/TY) * (128/TZ))  // 2048
#define NBOUND_HALF (NSAMP * 15 * 16384)      // per-direction boundary faces

// ---------------- global union-find (lock-free, link-to-min) ---------------
// Parent chains strictly decrease (roots only CAS-link to smaller indices;
// halving stores an ancestor) -> no cycles, find terminates, races safe.
__device__ __forceinline__ int find_root(int* L, int x) {
    int p = L[x];
    while (p != x) {
        int gp = L[p];
        if (gp != p) L[x] = gp;   // path halving
        x = gp;
        p = L[x];
    }
    return x;
}

__device__ __forceinline__ void unite(int* L, int a, int b) {
    a = find_root(L, a);
    b = find_root(L, b);
    while (a != b) {
        if (a < b) { int t = a; a = b; b = t; }   // a > b: link a under b
        int old = atomicCAS(&L[a], a, b);
        if (old == a) return;
        a = find_root(L, old);
        b = find_root(L, b);
    }
}

// ---------------- LDS union-find (same invariants) --------------------------
__device__ __forceinline__ int lfind(int* P, int x) {
    int p = P[x];
    while (p != x) {
        int gp = P[p];
        if (gp != p) P[x] = gp;
        x = gp;
        p = P[x];
    }
    return x;
}

__device__ __forceinline__ void lunite(int* P, int a, int b) {
    a = lfind(P, a);
    b = lfind(P, b);
    while (a != b) {
        if (a < b) { int t = a; a = b; b = t; }
        int old = atomicCAS(&P[a], a, b);
        if (old == a) return;
        a = lfind(P, old);
        b = lfind(P, b);
    }
}

// ---------------- kernels ---------------------------------------------------
// One block per 128x8x8 tile: threshold + full local CCL in LDS, then write
// labels as global indices of tile-local roots.  Reads/writes are disjoint
// per-tile, so L may alias g.
__global__ __launch_bounds__(BLK) void k_local(const float4* g4, int* L) {
    __shared__ int P[TVOX];
    int tile = blockIdx.x;
    int s  = tile >> 8;
    int tz = (tile >> 4) & 15;
    int ty = tile & 15;
    // global idx of local voxel l (= lx + 128*ly + 1024*lz):
    //   base + (l & 1023) + 16384*(l >> 10)
    size_t base = (size_t)s * NPS + 1024u * ty + 131072u * tz;
    int t = threadIdx.x;

    // phase 1: vectorized load + threshold into LDS parents
    for (int k = 0; k < 8; ++k) {
        int l = (t + 256 * k) * 4;
        size_t goff = base + (l & 1023) + 16384 * (size_t)(l >> 10);
        float4 v = g4[goff >> 2];
        P[l + 0] = (v.x > 0.5f) ? l + 0 : -1;
        P[l + 1] = (v.y > 0.5f) ? l + 1 : -1;
        P[l + 2] = (v.z > 0.5f) ? l + 2 : -1;
        P[l + 3] = (v.w > 0.5f) ? l + 3 : -1;
    }
    __syncthreads();

    // phase 2: local unions with -x, -y, -z neighbors
    for (int k = 0; k < 32; ++k) {
        int l = t + 256 * k;
        if (P[l] < 0) continue;
        int lx = l & 127, lyz = l >> 7;
        if (lx > 0       && P[l - 1]    >= 0) lunite(P, l, l - 1);
        if ((lyz & 7)    && P[l - 128]  >= 0) lunite(P, l, l - 128);
        if ((lyz >> 3)   && P[l - 1024] >= 0) lunite(P, l, l - 1024);
    }
    __syncthreads();

    // phase 3: flatten + write global labels (coalesced)
    for (int k = 0; k < 32; ++k) {
        int l = t + 256 * k;
        size_t g = base + (l & 1023) + 16384 * (size_t)(l >> 10);
        int out = -1;
        if (P[l] >= 0) {
            int r = lfind(P, l);
            out = (int)(base + (r & 1023) + 16384 * (size_t)(r >> 10));
        }
        L[g] = out;
    }
}

// Cross-tile unions: only boundary face pairs in y and z directions.
__global__ void k_bmerge(int* L) {
    int f = blockIdx.x * BLK + threadIdx.x;
    int dir = 0;
    if (f >= NBOUND_HALF) { dir = 1; f -= NBOUND_HALF; }
    int s   = f / (15 * 16384);
    int rem = f - s * (15 * 16384);
    int m  = rem >> 14;          // 0..14 boundary plane
    int pq = rem & 16383;
    int x  = pq & 127;
    int q  = pq >> 7;
    int i, j;
    if (dir == 0) {              // between y=8m+7 and y=8m+8
        i = s * NPS + x + 128 * (8 * m + 7) + 16384 * q;
        j = i + 128;
    } else {                     // between z=8m+7 and z=8m+8
        i = s * NPS + x + 128 * q + 16384 * (8 * m + 7);
        j = i + 16384;
    }
    if (L[i] >= 0 && L[j] >= 0) unite(L, i, j);
}

// Dedupe immediate parents per block in LDS, then ONE global find_root per
// distinct parent; flush (root, count) to global open-addressing hash.
__global__ void k_count(int* L, int* gk, int* gv, unsigned hmask) {
    __shared__ int hk[512];
    __shared__ int hv[512];
    int t = threadIdx.x;
    hk[t] = -1;        hv[t] = 0;
    hk[t + 256] = -1;  hv[t + 256] = 0;
    __syncthreads();

    int i = blockIdx.x * BLK + t;
    int p = L[i];
    if (p >= 0) {
        unsigned h = ((unsigned)p * 2654435761u) & 511u;
        for (int probe = 0; probe < 512; ++probe) {      // bounded (<=256 keys)
            int prev = atomicCAS(&hk[h], -1, p);
            if (prev == -1 || prev == p) { atomicAdd(&hv[h], 1); break; }
            h = (h + 1) & 511u;
        }
    }
    __syncthreads();

    for (int s = t; s < 512; s += BLK) {
        int k = hk[s];
        if (k < 0) continue;
        int root = find_root(L, k);
        if (root != k) L[k] = root;          // compress for other blocks
        unsigned h = ((unsigned)root * 2654435761u) & hmask;
        for (unsigned probe = 0; probe <= hmask; ++probe) {  // bounded
            int prev = atomicCAS(&gk[h], -1, root);
            if (prev == -1 || prev == root) { atomicAdd(&gv[h], hv[s]); break; }
            h = (h + 1) & hmask;
        }
    }
}

// Grid-stride hash scan with per-block LDS pre-reduction (Guideline 12).
// acc layout: largest[8] | ncomp[8] | total[8]
#define RED_BLOCKS 512
__global__ void k_reduce(const int* __restrict__ gk, const int* __restrict__ gv,
                         int nslots, int* __restrict__ acc) {
    __shared__ int s_mx[NSAMP], s_cnt[NSAMP], s_sum[NSAMP];
    int t = threadIdx.x;
    if (t < NSAMP) { s_mx[t] = 0; s_cnt[t] = 0; s_sum[t] = 0; }
    __syncthreads();

    for (int i = blockIdx.x * BLK + t; i < nslots; i += RED_BLOCKS * BLK) {
        int k = gk[i];
        if (k >= 0) {
            int c = gv[i];
            int b = k >> 21;                 // root / NPS -> sample index
            atomicMax(&s_mx[b], c);
            atomicAdd(&s_cnt[b], 1);
            atomicAdd(&s_sum[b], c);
        }
    }
    __syncthreads();

    if (t < NSAMP) {
        if (s_mx[t])  atomicMax(&acc[t], s_mx[t]);
        if (s_cnt[t]) {
            atomicAdd(&acc[NSAMP + t], s_cnt[t]);
            atomicAdd(&acc[2 * NSAMP + t], s_sum[t]);
        }
    }
}

__global__ void k_final(const int* __restrict__ acc, float* __restrict__ out) {
    if (threadIdx.x == 0 && blockIdx.x == 0) {
        float s = 0.0f;
        for (int b = 0; b < NSAMP; ++b) {
            int largest = acc[b];
            int ncomp   = acc[NSAMP + b];
            int total   = acc[2 * NSAMP + b];
            if (ncomp > 1)
                s += ((float)(total - largest)) / ((float)total + 1e-6f);
        }
        out[0] = 10.0f * s / (float)NSAMP;
    }
}

// ---------------- launch ----------------------------------------------------
extern "C" void kernel_launch(void* const* d_in, const int* in_sizes, int n_in,
                              void* d_out, int out_size, void* d_ws, size_t ws_size,
                              hipStream_t stream) {
    const float4* grid4 = (const float4*)d_in[0];
    float* out = (float*)d_out;
    char* ws = (char*)d_ws;

    const size_t LBYTES = (size_t)BN * 4;     // 64 MiB labels

    // Labels in d_ws if they fit, else in-place over the input grid
    // (k_local reads/writes tile-disjoint; harness restores inputs pre-launch).
    int* labels;
    size_t off = 0;
    if (ws_size >= LBYTES + (1u << 16) * 8 + 256) {
        labels = (int*)ws;
        off = LBYTES;
    } else {
        labels = (int*)d_in[0];
    }

    // Global hash: power-of-two slots in remaining ws, capped at 2^20.
    size_t remain = (ws_size > off + 256) ? (ws_size - off - 256) : 0;
    unsigned HS = 1u << 10;
    while ((size_t)(HS << 1) * 8 <= remain && HS < (1u << 20)) HS <<= 1;

    int* gk  = (int*)(ws + off);
    int* gv  = gk + HS;
    int* acc = gv + HS;

    hipMemsetAsync(acc, 0, 96, stream);
    hipMemsetAsync(gk, 0xFF, (size_t)HS * 4, stream);   // keys = -1
    hipMemsetAsync(gv, 0x00, (size_t)HS * 4, stream);

    k_local <<<NTILES, BLK, 0, stream>>>(grid4, labels);
    k_bmerge<<<2 * NBOUND_HALF / BLK, BLK, 0, stream>>>(labels);
    k_count <<<NBLK, BLK, 0, stream>>>(labels, gk, gv, HS - 1);
    k_reduce<<<RED_BLOCKS, BLK, 0, stream>>>(gk, gv, (int)HS, acc);
    k_final <<<1, 64, 0, stream>>>(acc, out);
}

// Round 5
// 801.884 us; speedup vs baseline: 4.0040x; 4.0040x over previous
//
#include <hip/hip_runtime.h>

#define BLK   256
#define NSAMP 8
#define NPS   (1 << 21)           // voxels per sample (128^3)
#define BN    (1 << 24)           // total voxels
#define NBLK  (BN / BLK)

// Tile: full-x rows, 8x8 in y/z -> 8192 voxels, 32 KiB LDS parents
#define TY 8
#define TZ 8
#define TVOX (128 * TY * TZ)                  // 8192
#define NTILES (NSAMP * (128/TY) * (128/TZ))  // 2048
#define NBOUND_HALF (NSAMP * 15 * 16384)      // per-direction boundary faces

// ---------------- global union-find (lock-free, link-to-min) ---------------
// Parent chains strictly decrease (roots only CAS-link to smaller indices;
// halving stores an ancestor) -> no cycles, find terminates, races safe.
__device__ __forceinline__ int find_root(int* L, int x) {
    int p = L[x];
    while (p != x) {
        int gp = L[p];
        if (gp != p) L[x] = gp;   // path halving
        x = gp;
        p = L[x];
    }
    return x;
}

__device__ __forceinline__ void unite(int* L, int a, int b) {
    a = find_root(L, a);
    b = find_root(L, b);
    while (a != b) {
        if (a < b) { int t = a; a = b; b = t; }   // a > b: link a under b
        int old = atomicCAS(&L[a], a, b);
        if (old == a) return;
        a = find_root(L, old);
        b = find_root(L, b);
    }
}

// ---------------- LDS union-find (same invariants) --------------------------
__device__ __forceinline__ int lfind(int* P, int x) {
    int p = P[x];
    while (p != x) {
        int gp = P[p];
        if (gp != p) P[x] = gp;
        x = gp;
        p = P[x];
    }
    return x;
}

__device__ __forceinline__ void lunite(int* P, int a, int b) {
    a = lfind(P, a);
    b = lfind(P, b);
    while (a != b) {
        if (a < b) { int t = a; a = b; b = t; }
        int old = atomicCAS(&P[a], a, b);
        if (old == a) return;
        a = lfind(P, old);
        b = lfind(P, b);
    }
}

// ---------------- kernels ---------------------------------------------------
// One block per 128x8x8 tile.  Local CCL fully in LDS; per-local-root counts
// packed into the high 16 bits of the LDS parent word (count <= 8192).
// Outputs (both tile-disjoint, so C may overwrite the input grid):
//   L[g] = global index of tile-local root (or -1 for background)
//   C[g] = component count at tile-local roots, 0 elsewhere
__global__ __launch_bounds__(BLK) void k_local(const float4* __restrict__ g4,
                                               int* __restrict__ L,
                                               int* __restrict__ C) {
    __shared__ int P[TVOX];
    int tile = blockIdx.x;
    int s  = tile >> 8;
    int tz = (tile >> 4) & 15;
    int ty = tile & 15;
    // global idx of local voxel l (= lx + 128*ly + 1024*lz):
    //   base + (l & 1023) + 16384*(l >> 10)
    size_t base = (size_t)s * NPS + 1024u * ty + 131072u * tz;
    int t = threadIdx.x;

    // phase 1: vectorized load + threshold into LDS parents
    #pragma unroll
    for (int k = 0; k < 8; ++k) {
        int l = (t + 256 * k) * 4;
        size_t goff = base + (l & 1023) + 16384 * (size_t)(l >> 10);
        float4 v = g4[goff >> 2];
        P[l + 0] = (v.x > 0.5f) ? l + 0 : -1;
        P[l + 1] = (v.y > 0.5f) ? l + 1 : -1;
        P[l + 2] = (v.z > 0.5f) ? l + 2 : -1;
        P[l + 3] = (v.w > 0.5f) ? l + 3 : -1;
    }
    __syncthreads();

    // phase 2: local unions with -x, -y, -z neighbors
    #pragma unroll
    for (int k = 0; k < 32; ++k) {
        int l = t + 256 * k;
        if (P[l] < 0) continue;
        int lx = l & 127, lyz = l >> 7;
        if (lx > 0       && P[l - 1]    >= 0) lunite(P, l, l - 1);
        if ((lyz & 7)    && P[l - 128]  >= 0) lunite(P, l, l - 128);
        if ((lyz >> 3)   && P[l - 1024] >= 0) lunite(P, l, l - 1024);
    }
    __syncthreads();

    // phase 3a: resolve roots into registers (static indexing -> VGPRs)
    int r[32];
    #pragma unroll
    for (int k = 0; k < 32; ++k) {
        int l = t + 256 * k;
        r[k] = (P[l] >= 0) ? lfind(P, l) : -1;
    }
    __syncthreads();

    // phase 3b: commit full compression (no concurrent walkers now)
    #pragma unroll
    for (int k = 0; k < 32; ++k) {
        int l = t + 256 * k;
        if (r[k] >= 0) P[l] = r[k];
    }
    __syncthreads();

    // phase 3c: count into high 16 bits of the root's parent word
    #pragma unroll
    for (int k = 0; k < 32; ++k) {
        if (r[k] >= 0) atomicAdd(&P[r[k]], 0x10000);
    }
    __syncthreads();

    // phase 3d: write labels + counts (coalesced, tile-disjoint)
    #pragma unroll
    for (int k = 0; k < 32; ++k) {
        int l = t + 256 * k;
        size_t g = base + (l & 1023) + 16384 * (size_t)(l >> 10);
        if (r[k] >= 0) {
            int rr = r[k];
            L[g] = (int)(base + (rr & 1023) + 16384 * (size_t)(rr >> 10));
            C[g] = (rr == l) ? ((unsigned)P[l] >> 16) : 0;
        } else {
            L[g] = -1;
            C[g] = 0;
        }
    }
}

// Cross-tile unions: only boundary face pairs in y and z directions.
__global__ void k_bmerge(int* L) {
    int f = blockIdx.x * BLK + threadIdx.x;
    int dir = 0;
    if (f >= NBOUND_HALF) { dir = 1; f -= NBOUND_HALF; }
    int s   = f / (15 * 16384);
    int rem = f - s * (15 * 16384);
    int m  = rem >> 14;          // 0..14 boundary plane
    int pq = rem & 16383;
    int x  = pq & 127;
    int q  = pq >> 7;
    int i, j;
    if (dir == 0) {              // between y=8m+7 and y=8m+8
        i = s * NPS + x + 128 * (8 * m + 7) + 16384 * q;
        j = i + 128;
    } else {                     // between z=8m+7 and z=8m+8
        i = s * NPS + x + 128 * q + 16384 * (8 * m + 7);
        j = i + 16384;
    }
    if (L[i] >= 0 && L[j] >= 0) unite(L, i, j);
}

// Scan the sparse count array (int4); only nonzero entries (~1.5%) chase the
// global union-find.  Per-block LDS hash accumulates (final_root, count_sum)
// before flushing to the global open-addressing hash (Guideline 12).
#define SCAN_BLOCKS (BN / (BLK * 4))          // 16384
__global__ void k_scan(const int4* __restrict__ C4, int* L,
                       int* gk, int* gv, unsigned hmask) {
    __shared__ int hk[2048];
    __shared__ int hv[2048];
    int t = threadIdx.x;
    #pragma unroll
    for (int k = 0; k < 8; ++k) { hk[t + 256 * k] = -1; hv[t + 256 * k] = 0; }
    __syncthreads();

    int vi = blockIdx.x * BLK + t;
    int4 c = C4[vi];
    int gbase = vi * 4;
    #pragma unroll
    for (int j = 0; j < 4; ++j) {
        int cnt = (j == 0) ? c.x : (j == 1) ? c.y : (j == 2) ? c.z : c.w;
        if (cnt > 0) {
            int root = find_root(L, gbase + j);
            unsigned h = ((unsigned)root * 2654435761u) & 2047u;
            for (int probe = 0; probe < 2048; ++probe) {  // keys <= 1024: safe
                int prev = atomicCAS(&hk[h], -1, root);
                if (prev == -1 || prev == root) { atomicAdd(&hv[h], cnt); break; }
                h = (h + 1) & 2047u;
            }
        }
    }
    __syncthreads();

    for (int sIdx = t; sIdx < 2048; sIdx += BLK) {
        int k = hk[sIdx];
        if (k < 0) continue;
        unsigned h = ((unsigned)k * 2654435761u) & hmask;
        for (unsigned probe = 0; probe <= hmask; ++probe) {  // bounded
            int prev = atomicCAS(&gk[h], -1, k);
            if (prev == -1 || prev == k) { atomicAdd(&gv[h], hv[sIdx]); break; }
            h = (h + 1) & hmask;
        }
    }
}

// Grid-stride hash scan with per-block LDS pre-reduction (Guideline 12).
// acc layout: largest[8] | ncomp[8] | total[8]
#define RED_BLOCKS 512
__global__ void k_reduce(const int* __restrict__ gk, const int* __restrict__ gv,
                         int nslots, int* __restrict__ acc) {
    __shared__ int s_mx[NSAMP], s_cnt[NSAMP], s_sum[NSAMP];
    int t = threadIdx.x;
    if (t < NSAMP) { s_mx[t] = 0; s_cnt[t] = 0; s_sum[t] = 0; }
    __syncthreads();

    for (int i = blockIdx.x * BLK + t; i < nslots; i += RED_BLOCKS * BLK) {
        int k = gk[i];
        if (k >= 0) {
            int c = gv[i];
            int b = k >> 21;                 // root / NPS -> sample index
            atomicMax(&s_mx[b], c);
            atomicAdd(&s_cnt[b], 1);
            atomicAdd(&s_sum[b], c);
        }
    }
    __syncthreads();

    if (t < NSAMP) {
        if (s_mx[t])  atomicMax(&acc[t], s_mx[t]);
        if (s_cnt[t]) {
            atomicAdd(&acc[NSAMP + t], s_cnt[t]);
            atomicAdd(&acc[2 * NSAMP + t], s_sum[t]);
        }
    }
}

__global__ void k_final(const int* __restrict__ acc, float* __restrict__ out) {
    if (threadIdx.x == 0 && blockIdx.x == 0) {
        float s = 0.0f;
        for (int b = 0; b < NSAMP; ++b) {
            int largest = acc[b];
            int ncomp   = acc[NSAMP + b];
            int total   = acc[2 * NSAMP + b];
            if (ncomp > 1)
                s += ((float)(total - largest)) / ((float)total + 1e-6f);
        }
        out[0] = 10.0f * s / (float)NSAMP;
    }
}

// ---------------- launch ----------------------------------------------------
extern "C" void kernel_launch(void* const* d_in, const int* in_sizes, int n_in,
                              void* d_out, int out_size, void* d_ws, size_t ws_size,
                              hipStream_t stream) {
    const float4* grid4 = (const float4*)d_in[0];
    int* C = (int*)d_in[0];       // count array overwrites the dead input grid
                                  // (tile-disjoint read->write inside k_local;
                                  //  harness restores inputs before each launch)
    float* out = (float*)d_out;
    char* ws = (char*)d_ws;

    const size_t LBYTES = (size_t)BN * 4;     // 64 MiB labels
    int* labels = (int*)ws;
    size_t off = LBYTES;

    // Global hash: power-of-two slots in remaining ws, capped at 2^20.
    size_t remain = (ws_size > off + 256) ? (ws_size - off - 256) : 0;
    unsigned HS = 1u << 10;
    while ((size_t)(HS << 1) * 8 <= remain && HS < (1u << 20)) HS <<= 1;

    int* gk  = (int*)(ws + off);
    int* gv  = gk + HS;
    int* acc = gv + HS;

    hipMemsetAsync(acc, 0, 96, stream);
    hipMemsetAsync(gk, 0xFF, (size_t)HS * 4, stream);   // keys = -1
    hipMemsetAsync(gv, 0x00, (size_t)HS * 4, stream);

    k_local <<<NTILES, BLK, 0, stream>>>(grid4, labels, C);
    k_bmerge<<<2 * NBOUND_HALF / BLK, BLK, 0, stream>>>(labels);
    k_scan  <<<SCAN_BLOCKS, BLK, 0, stream>>>((const int4*)C, labels, gk, gv, HS - 1);
    k_reduce<<<RED_BLOCKS, BLK, 0, stream>>>(gk, gv, (int)HS, acc);
    k_final <<<1, 64, 0, stream>>>(acc, out);
}